// Round 12
// baseline (334.558 us; speedup 1.0000x reference)
//
#include <hip/hip_runtime.h>
#include <math.h>

#define H 64
#define NCONV 3
#define NGRAPHS 64
#define NCLASSES 10
#define TBL 8192
#define TROWS (TBL + 1)
#define CAP 6144          // coarse-bucket capacity: mean 4704 + ~21 sigma
#define EPT 8             // edges/thread in coarse_part

typedef unsigned short bfu;

__device__ __forceinline__ float bf2f(bfu u) {
    return __uint_as_float(((unsigned int)u) << 16);
}
__device__ __forceinline__ bfu f2bf(float f) {
    unsigned int x = __float_as_uint(f);
    return (bfu)((x + 0x7FFF + ((x >> 16) & 1)) >> 16);
}
__device__ __forceinline__ float softplus_f(float x) {
    return fmaxf(x, 0.f) + log1pf(expf(-fabsf(x)));
}
__device__ __forceinline__ float bflo(unsigned int u) { return __uint_as_float(u << 16); }
__device__ __forceinline__ float bfhi(unsigned int u) { return __uint_as_float(u & 0xFFFF0000u); }

// packed edge record: bits 0-16 = src, bits 17-30 = quantized d index
__device__ __forceinline__ unsigned int ld_rec_nt(const unsigned int* p) {
    return __builtin_nontemporal_load(p);
}
#define REC_SRC(u) ((u) & 0x1FFFFu)
#define REC_T(u)   ((u) >> 17)

// ---------------- table build: tabs[4][TROWS][H] in bf16 -------------------
__global__ void build_tables(const float* __restrict__ W_emb1, const float* __restrict__ b_emb1,
                             const float* __restrict__ W_emb2, const float* __restrict__ b_emb2,
                             const float* __restrict__ fW1, const float* __restrict__ fb1,
                             const float* __restrict__ fW2, const float* __restrict__ fb2,
                             bfu* __restrict__ tabs)
{
    int which = blockIdx.y;
    const float *W1, *b1, *W2, *b2;
    if (which == 0) { W1 = W_emb1; b1 = b_emb1; W2 = W_emb2; b2 = b_emb2; }
    else {
        int l = which - 1;
        W1 = fW1 + l * H * H; b1 = fb1 + l * H;
        W2 = fW2 + l * H * H; b2 = fb2 + l * H;
    }

    __shared__ float sW1[H * H], sW2[H * H];
    __shared__ float sb1[H], sb2[H];
    __shared__ float sha[4][H], shb[4][H];

    int tid = threadIdx.x;
    for (int i = tid; i < H * H; i += 256) { sW1[i] = W1[i]; sW2[i] = W2[i]; }
    if (tid < H) sb1[tid] = b1[tid];
    else if (tid < 2 * H) sb2[tid - H] = b2[tid - H];
    __syncthreads();

    int wave = tid >> 6, lane = tid & 63;
    int base = blockIdx.x * 64;
    int lim  = min(base + 64, TROWS);

    for (int r = base + wave; r < lim; r += 4) {
        float dv   = (float)r / (float)TBL;
        float mu   = (float)lane / (float)(H - 1);
        float diff = dv - mu;
        float cut  = 0.5f * (cosf(3.14159265358979323846f * dv) + 1.0f);
        float bfj  = expf(-(float)H * diff * diff) * cut;

        sha[wave][lane] = bfj;
        float a = sb1[lane];
        #pragma unroll
        for (int i = 0; i < H; ++i) a = fmaf(sha[wave][i], sW1[i * H + lane], a);
        shb[wave][lane] = softplus_f(a);
        float a2 = sb2[lane];
        #pragma unroll
        for (int i = 0; i < H; ++i) a2 = fmaf(shb[wave][i], sW2[i * H + lane], a2);

        tabs[((size_t)which * TROWS + r) * H + lane] = f2bf(a2);
    }
}

// ---------------- CSR build: two-level LDS counting sort -------------------
__global__ void coarse_part(const int* __restrict__ src, const int* __restrict__ dst,
                            const float* __restrict__ d, int* __restrict__ ccur,
                            unsigned long long* __restrict__ cbuf, int E, int ncb)
{
    __shared__ int lcnt[256];
    __shared__ int lbase[256];
    int tid = threadIdx.x;
    int e0  = blockIdx.x * (256 * EPT);

    lcnt[tid] = 0;
    __syncthreads();

    int mybin[EPT], myrank[EPT];
    unsigned long long myrec[EPT];
    #pragma unroll
    for (int k = 0; k < EPT; ++k) {
        int e = e0 + k * 256 + tid;
        mybin[k] = -1;
        if (e < E) {
            int v = dst[e];
            int bin = v >> 8;
            float dv = fminf(fmaxf(d[e], 0.f), 1.f);
            int t = (int)(dv * (float)TBL + 0.5f);
            t = min(t, TBL);
            unsigned int p31 = (unsigned int)src[e] | ((unsigned int)t << 17);
            myrec[k]  = (unsigned long long)p31 | ((unsigned long long)(v & 255) << 32);
            mybin[k]  = bin;
            myrank[k] = atomicAdd(&lcnt[bin], 1);
        }
    }
    __syncthreads();

    {
        int c = (tid < ncb) ? lcnt[tid] : 0;
        lbase[tid] = (c > 0) ? atomicAdd(&ccur[tid], c) : 0;
    }
    __syncthreads();

    #pragma unroll
    for (int k = 0; k < EPT; ++k) {
        if (mybin[k] >= 0) {
            cbuf[(size_t)mybin[k] * CAP + lbase[mybin[k]] + myrank[k]] = myrec[k];
        }
    }
}

__global__ void cscan(const int* __restrict__ ccur, int* __restrict__ cstart,
                      int* __restrict__ off, int E, int N, int ncb)
{
    __shared__ int s[256];
    int t = threadIdx.x;
    int v = (t < ncb) ? ccur[t] : 0;
    s[t] = v;
    __syncthreads();
    for (int o = 1; o < 256; o <<= 1) {
        int u = (t >= o) ? s[t - o] : 0;
        __syncthreads();
        s[t] += u;
        __syncthreads();
    }
    if (t < ncb) cstart[t] = s[t] - v;
    if (t == 0) off[N] = E;
}

__global__ void fine_sort(const unsigned long long* __restrict__ cbuf,
                          const int* __restrict__ ccur, const int* __restrict__ cstart,
                          int* __restrict__ off, unsigned int* __restrict__ recs, int N)
{
    __shared__ int lcnt[256];
    __shared__ int ss[256];
    __shared__ int lcur[256];
    int bin  = blockIdx.x;
    int tid  = threadIdx.x;
    int cnt  = ccur[bin];
    int base = cstart[bin];
    const unsigned long long* buf = cbuf + (size_t)bin * CAP;

    lcnt[tid] = 0;
    __syncthreads();
    for (int i = tid; i < cnt; i += 256) {
        int j = (int)((buf[i] >> 32) & 255);
        atomicAdd(&lcnt[j], 1);
    }
    __syncthreads();
    int v = lcnt[tid];
    ss[tid] = v;
    __syncthreads();
    for (int o = 1; o < 256; o <<= 1) {
        int u = (tid >= o) ? ss[tid - o] : 0;
        __syncthreads();
        ss[tid] += u;
        __syncthreads();
    }
    int excl = ss[tid] - v;
    lcur[tid] = excl;
    int node = bin * 256 + tid;
    if (node < N) off[node] = base + excl;
    __syncthreads();
    for (int i = tid; i < cnt; i += 256) {
        unsigned long long r = buf[i];
        int j = (int)((r >> 32) & 255);
        int pos = base + atomicAdd(&lcur[j], 1);
        recs[pos] = (unsigned int)(r & 0x7FFFFFFFu);
    }
}

// ---------------- embedding fused with W_in0 -------------------
// Quarter-wave per edge: lane = q*16+i, quarter q streams edges b+q, b+q+4,..
// Each lane loads uint2 (4 columns). 3-stage pipeline.
__global__ void emb_fused(const int* __restrict__ off, const unsigned int* __restrict__ recs,
                          const bfu* __restrict__ tab, const float* __restrict__ W,
                          const float* __restrict__ bvec, bfu* __restrict__ yout, int N)
{
    __shared__ float sW[H * H];
    __shared__ float sb[H];
    __shared__ float sx[4][H];
    int tid = threadIdx.x;
    for (int i = tid; i < H * H; i += 256) sW[i] = W[i];
    if (tid < H) sb[tid] = bvec[tid];
    __syncthreads();

    const uint2* tab2 = (const uint2*)tab;

    int wave = tid >> 6, lane = tid & 63;
    int q  = lane >> 4;
    int li = lane & 15;

    for (int k = 0; k < 4; ++k) {
        int node = blockIdx.x * 16 + k * 4 + wave;
        if (node >= N) continue;
        int b = off[node], en = off[node + 1];
        int deg   = en - b;
        int nfull = deg >> 2;

        float a0 = 0.f, a1 = 0.f, a2 = 0.f, a3 = 0.f;
        int p = b + q;

        if (nfull >= 2) {
            unsigned int u0 = ld_rec_nt(recs + p);
            unsigned int u1 = ld_rec_nt(recs + p + 4);
            p += 8;
            uint2 tv0 = tab2[(size_t)REC_T(u0) * 16 + li];
            for (int it = 2; it < nfull; ++it) {
                unsigned int u2 = ld_rec_nt(recs + p);
                p += 4;
                uint2 tv1 = tab2[(size_t)REC_T(u1) * 16 + li];
                a0 += bflo(tv0.x); a1 += bfhi(tv0.x);
                a2 += bflo(tv0.y); a3 += bfhi(tv0.y);
                u1 = u2; tv0 = tv1;
            }
            uint2 tv1 = tab2[(size_t)REC_T(u1) * 16 + li];
            a0 += bflo(tv0.x); a1 += bfhi(tv0.x);
            a2 += bflo(tv0.y); a3 += bfhi(tv0.y);
            a0 += bflo(tv1.x); a1 += bfhi(tv1.x);
            a2 += bflo(tv1.y); a3 += bfhi(tv1.y);
        } else if (nfull == 1) {
            unsigned int u0 = ld_rec_nt(recs + p);
            uint2 tv0 = tab2[(size_t)REC_T(u0) * 16 + li];
            a0 += bflo(tv0.x); a1 += bfhi(tv0.x);
            a2 += bflo(tv0.y); a3 += bfhi(tv0.y);
        }
        int r = deg & 3;
        if (q < r) {
            unsigned int u = ld_rec_nt(recs + b + 4 * nfull + q);
            uint2 tv = tab2[(size_t)REC_T(u) * 16 + li];
            a0 += bflo(tv.x); a1 += bfhi(tv.x);
            a2 += bflo(tv.y); a3 += bfhi(tv.y);
        }

        // merge quarters: lanes sharing li hold same 4 columns
        a0 += __shfl_xor(a0, 16); a0 += __shfl_xor(a0, 32);
        a1 += __shfl_xor(a1, 16); a1 += __shfl_xor(a1, 32);
        a2 += __shfl_xor(a2, 16); a2 += __shfl_xor(a2, 32);
        a3 += __shfl_xor(a3, 16); a3 += __shfl_xor(a3, 32);
        if (lane < 16) {
            sx[wave][4 * li + 0] = a0;
            sx[wave][4 * li + 1] = a1;
            sx[wave][4 * li + 2] = a2;
            sx[wave][4 * li + 3] = a3;
        }
        float o = sb[lane];
        #pragma unroll
        for (int i = 0; i < H; ++i) o = fmaf(sx[wave][i], sW[i * H + lane], o);
        yout[(size_t)node * H + lane] = f2bf(o);
    }
}

// ---------------- conv layer, fully fused -------------------
// Quarter-wave per edge, uint2 loads, 3-stage pipeline; epilogue applies
// W_out (+relu) and optionally next layer's W_in, both as packed-bf16 LDS.
template <bool LAST>
__global__ void conv_fused_k(const int* __restrict__ off, const unsigned int* __restrict__ recs,
                             const bfu* __restrict__ tab, const bfu* __restrict__ y,
                             const float* __restrict__ W_out, const float* __restrict__ b_out,
                             const float* __restrict__ W_in, const float* __restrict__ b_in,
                             bfu* __restrict__ yout, float* __restrict__ xout, int N)
{
    __shared__ unsigned int sWo[H * H / 2];
    __shared__ unsigned int sWi[H * H / 2];
    __shared__ float sbo[H], sbi[H];
    __shared__ float sx[4][H];
    int tid = threadIdx.x;
    for (int i = tid; i < H * H / 2; i += 256) {
        int i2 = i >> 6, l = i & 63;
        sWo[i] = (unsigned int)f2bf(W_out[(2 * i2) * H + l]) |
                 ((unsigned int)f2bf(W_out[(2 * i2 + 1) * H + l]) << 16);
        if (!LAST)
            sWi[i] = (unsigned int)f2bf(W_in[(2 * i2) * H + l]) |
                     ((unsigned int)f2bf(W_in[(2 * i2 + 1) * H + l]) << 16);
    }
    if (tid < H) sbo[tid] = b_out[tid];
    else if (!LAST && tid < 2 * H) sbi[tid - H] = b_in[tid - H];
    __syncthreads();

    const uint2* tab2 = (const uint2*)tab;
    const uint2* y2   = (const uint2*)y;

    int wave = tid >> 6, lane = tid & 63;
    int q  = lane >> 4;
    int li = lane & 15;

    for (int k = 0; k < 4; ++k) {
        int node = blockIdx.x * 16 + k * 4 + wave;
        if (node >= N) continue;
        int b = off[node], en = off[node + 1];
        int deg   = en - b;
        int nfull = deg >> 2;

        float a0 = 0.f, a1 = 0.f, a2 = 0.f, a3 = 0.f;
        int p = b + q;

        if (nfull >= 2) {
            unsigned int u0 = ld_rec_nt(recs + p);
            unsigned int u1 = ld_rec_nt(recs + p + 4);
            p += 8;
            uint2 tv0 = tab2[(size_t)REC_T(u0) * 16 + li];
            uint2 yv0 = y2[(size_t)REC_SRC(u0) * 16 + li];
            for (int it = 2; it < nfull; ++it) {
                unsigned int u2 = ld_rec_nt(recs + p);
                p += 4;
                uint2 tv1 = tab2[(size_t)REC_T(u1) * 16 + li];
                uint2 yv1 = y2[(size_t)REC_SRC(u1) * 16 + li];
                a0 = fmaf(bflo(yv0.x), bflo(tv0.x), a0);
                a1 = fmaf(bfhi(yv0.x), bfhi(tv0.x), a1);
                a2 = fmaf(bflo(yv0.y), bflo(tv0.y), a2);
                a3 = fmaf(bfhi(yv0.y), bfhi(tv0.y), a3);
                u1 = u2; tv0 = tv1; yv0 = yv1;
            }
            uint2 tv1 = tab2[(size_t)REC_T(u1) * 16 + li];
            uint2 yv1 = y2[(size_t)REC_SRC(u1) * 16 + li];
            a0 = fmaf(bflo(yv0.x), bflo(tv0.x), a0);
            a1 = fmaf(bfhi(yv0.x), bfhi(tv0.x), a1);
            a2 = fmaf(bflo(yv0.y), bflo(tv0.y), a2);
            a3 = fmaf(bfhi(yv0.y), bfhi(tv0.y), a3);
            a0 = fmaf(bflo(yv1.x), bflo(tv1.x), a0);
            a1 = fmaf(bfhi(yv1.x), bfhi(tv1.x), a1);
            a2 = fmaf(bflo(yv1.y), bflo(tv1.y), a2);
            a3 = fmaf(bfhi(yv1.y), bfhi(tv1.y), a3);
        } else if (nfull == 1) {
            unsigned int u0 = ld_rec_nt(recs + p);
            uint2 tv0 = tab2[(size_t)REC_T(u0) * 16 + li];
            uint2 yv0 = y2[(size_t)REC_SRC(u0) * 16 + li];
            a0 = fmaf(bflo(yv0.x), bflo(tv0.x), a0);
            a1 = fmaf(bfhi(yv0.x), bfhi(tv0.x), a1);
            a2 = fmaf(bflo(yv0.y), bflo(tv0.y), a2);
            a3 = fmaf(bfhi(yv0.y), bfhi(tv0.y), a3);
        }
        int r = deg & 3;
        if (q < r) {
            unsigned int u = ld_rec_nt(recs + b + 4 * nfull + q);
            uint2 tv = tab2[(size_t)REC_T(u) * 16 + li];
            uint2 yv = y2[(size_t)REC_SRC(u) * 16 + li];
            a0 = fmaf(bflo(yv.x), bflo(tv.x), a0);
            a1 = fmaf(bfhi(yv.x), bfhi(tv.x), a1);
            a2 = fmaf(bflo(yv.y), bflo(tv.y), a2);
            a3 = fmaf(bfhi(yv.y), bfhi(tv.y), a3);
        }

        a0 += __shfl_xor(a0, 16); a0 += __shfl_xor(a0, 32);
        a1 += __shfl_xor(a1, 16); a1 += __shfl_xor(a1, 32);
        a2 += __shfl_xor(a2, 16); a2 += __shfl_xor(a2, 32);
        a3 += __shfl_xor(a3, 16); a3 += __shfl_xor(a3, 32);
        if (lane < 16) {
            sx[wave][4 * li + 0] = a0;
            sx[wave][4 * li + 1] = a1;
            sx[wave][4 * li + 2] = a2;
            sx[wave][4 * li + 3] = a3;
        }
        float o = sbo[lane];
        #pragma unroll
        for (int i2 = 0; i2 < H / 2; ++i2) {
            unsigned int u = sWo[i2 * H + lane];
            o = fmaf(sx[wave][2 * i2],     bflo(u), o);
            o = fmaf(sx[wave][2 * i2 + 1], bfhi(u), o);
        }
        o = fmaxf(o, 0.f);
        if (LAST) {
            xout[(size_t)node * H + lane] = o;
        } else {
            sx[wave][lane] = o;   // same-wave reuse: prior reads are complete
            float o2 = sbi[lane];
            #pragma unroll
            for (int i2 = 0; i2 < H / 2; ++i2) {
                unsigned int u = sWi[i2 * H + lane];
                o2 = fmaf(sx[wave][2 * i2],     bflo(u), o2);
                o2 = fmaf(sx[wave][2 * i2 + 1], bfhi(u), o2);
            }
            yout[(size_t)node * H + lane] = f2bf(o2);
        }
    }
}

// ---------------- pooling (sorted gid, run-length flush) -------------------
__global__ void pool_kernel(const float* __restrict__ x, const int* __restrict__ gid,
                            float* __restrict__ pooled, float* __restrict__ counts, int N)
{
    int wavesPerBlock = blockDim.x >> 6;
    int wid  = blockIdx.x * wavesPerBlock + (threadIdx.x >> 6);
    int lane = threadIdx.x & 63;
    int totalWaves = gridDim.x * wavesPerBlock;
    int chunk = (N + totalWaves - 1) / totalWaves;
    int beg = wid * chunk, end = min(beg + chunk, N);
    if (beg >= end) return;

    float acc = 0.f;
    int cur = -1, cnt = 0;
    for (int n = beg; n < end; ++n) {
        int g = gid[n];
        if (g != cur) {
            if (cur >= 0) {
                atomicAdd(&pooled[(size_t)cur * H + lane], acc);
                if (lane == 0) atomicAdd(&counts[cur], (float)cnt);
            }
            cur = g; acc = 0.f; cnt = 0;
        }
        acc += x[(size_t)n * H + lane];
        cnt++;
    }
    atomicAdd(&pooled[(size_t)cur * H + lane], acc);
    if (lane == 0) atomicAdd(&counts[cur], (float)cnt);
}

// ---------------- head -------------------
__global__ void head_kernel(const float* __restrict__ pooled, const float* __restrict__ counts,
                            const float* __restrict__ Wfc, const float* __restrict__ bfc,
                            float* __restrict__ out)
{
    int g = blockIdx.x;
    int c = threadIdx.x;
    __shared__ float logits[NCLASSES];
    float cnt = fmaxf(counts[g], 1.0f);
    if (c < NCLASSES) {
        float acc = bfc[c];
        #pragma unroll
        for (int i = 0; i < H; ++i)
            acc = fmaf(pooled[(size_t)g * H + i] / cnt, Wfc[i * NCLASSES + c], acc);
        logits[c] = acc;
    }
    __syncthreads();
    if (c < NCLASSES) {
        float m = -INFINITY;
        #pragma unroll
        for (int k = 0; k < NCLASSES; ++k) m = fmaxf(m, logits[k]);
        float s = 0.f;
        #pragma unroll
        for (int k = 0; k < NCLASSES; ++k) s += expf(logits[k] - m);
        out[g * NCLASSES + c] = logits[c] - m - logf(s);
    }
}

extern "C" void kernel_launch(void* const* d_in, const int* in_sizes, int n_in,
                              void* d_out, int out_size, void* d_ws, size_t ws_size,
                              hipStream_t stream)
{
    const float* d_d    = (const float*)d_in[0];
    const float* W_emb1 = (const float*)d_in[1];
    const float* b_emb1 = (const float*)d_in[2];
    const float* W_emb2 = (const float*)d_in[3];
    const float* b_emb2 = (const float*)d_in[4];
    const float* fW1    = (const float*)d_in[5];
    const float* fb1    = (const float*)d_in[6];
    const float* fW2    = (const float*)d_in[7];
    const float* fb2    = (const float*)d_in[8];
    const float* W_in   = (const float*)d_in[9];
    const float* b_in   = (const float*)d_in[10];
    const float* W_out  = (const float*)d_in[11];
    const float* b_out  = (const float*)d_in[12];
    const float* W_fc   = (const float*)d_in[13];
    const float* b_fc   = (const float*)d_in[14];
    const int*   src    = (const int*)d_in[15];
    const int*   dst    = (const int*)d_in[16];
    const int*   gid    = (const int*)d_in[17];

    const int E = in_sizes[0];
    const int N = in_sizes[17];
    const int ncb = (N + 255) >> 8;   // coarse buckets (<= 256)

    float* out = (float*)d_out;

    // workspace layout (x3 and cbuf share a union region — disjoint lifetimes)
    char* base = (char*)d_ws;
    unsigned int* recs = (unsigned int*)base;   base += (size_t)E * 4;
    bfu*  tabs   = (bfu*)base;                  base += (size_t)4 * TROWS * H * 2;
    bfu*  yA     = (bfu*)base;                  base += (size_t)N * H * 2;
    bfu*  yB     = (bfu*)base;                  base += (size_t)N * H * 2;
    size_t usz   = (size_t)N * H * 4;
    size_t csz   = (size_t)ncb * CAP * 8;
    char* uni    = base;                        base += (usz > csz ? usz : csz);
    float* x3    = (float*)uni;
    unsigned long long* cbuf = (unsigned long long*)uni;
    float* pooled= (float*)base;                base += (size_t)NGRAPHS * H * 4;
    float* counts= (float*)base;                base += (size_t)NGRAPHS * 4;
    int*  off    = (int*)base;                  base += (size_t)(N + 1) * 4;
    int*  ccur   = (int*)base;                  base += 256 * 4;
    int*  cstart = (int*)base;                  base += 256 * 4;

    const int node_blocks16 = (N + 15) / 16;
    const int part_blocks   = (E + 256 * EPT - 1) / (256 * EPT);

    // 1. bf16 MLP lookup tables
    dim3 tg((TROWS + 63) / 64, 4);
    build_tables<<<tg, 256, 0, stream>>>(W_emb1, b_emb1, W_emb2, b_emb2,
                                         fW1, fb1, fW2, fb2, tabs);

    // 2. CSR build: two-level LDS counting sort (no mass device atomics)
    hipMemsetAsync(ccur, 0, 256 * 4, stream);
    coarse_part<<<part_blocks, 256, 0, stream>>>(src, dst, d_d, ccur, cbuf, E, ncb);
    cscan<<<1, 256, 0, stream>>>(ccur, cstart, off, E, N, ncb);
    fine_sort<<<ncb, 256, 0, stream>>>(cbuf, ccur, cstart, off, recs, N);

    // 3. embedding + W_in0 -> yA
    emb_fused<<<node_blocks16, 256, 0, stream>>>(off, recs, tabs, W_in, b_in, yA, N);

    // 4. conv layers, fully fused (out-proj + next in-proj in epilogue)
    conv_fused_k<false><<<node_blocks16, 256, 0, stream>>>(
        off, recs, tabs + (size_t)1 * TROWS * H, yA,
        W_out, b_out, W_in + (size_t)1 * H * H, b_in + (size_t)1 * H, yB, nullptr, N);
    conv_fused_k<false><<<node_blocks16, 256, 0, stream>>>(
        off, recs, tabs + (size_t)2 * TROWS * H, yB,
        W_out + (size_t)1 * H * H, b_out + (size_t)1 * H,
        W_in + (size_t)2 * H * H, b_in + (size_t)2 * H, yA, nullptr, N);
    conv_fused_k<true><<<node_blocks16, 256, 0, stream>>>(
        off, recs, tabs + (size_t)3 * TROWS * H, yA,
        W_out + (size_t)2 * H * H, b_out + (size_t)2 * H,
        nullptr, nullptr, nullptr, x3, N);

    // 5. pooling
    hipMemsetAsync(pooled, 0, ((size_t)NGRAPHS * H + NGRAPHS) * 4, stream);
    pool_kernel<<<128, 256, 0, stream>>>(x3, gid, pooled, counts, N);

    // 6. head
    head_kernel<<<NGRAPHS, 64, 0, stream>>>(pooled, counts, W_fc, b_fc, out);
}

// Round 14
// 314.476 us; speedup vs baseline: 1.0639x; 1.0639x over previous
//
#include <hip/hip_runtime.h>
#include <math.h>

#define H 64
#define NCONV 3
#define NGRAPHS 64
#define NCLASSES 10
#define TBL 8192
#define TROWS (TBL + 1)
#define CAP 6144          // coarse-bucket capacity: mean 4704 + ~21 sigma
#define EPT 8             // edges/thread in coarse_part
#define YSCL 0.0625f      // y stored scaled by 1/16 (exact)
#define YISCL 16.0f

typedef _Float16 h2 __attribute__((ext_vector_type(2)));

__device__ __forceinline__ h2 u2h(unsigned int u) { return __builtin_bit_cast(h2, u); }
__device__ __forceinline__ unsigned int pack2h(float a, float b) {
    h2 t; t.x = (_Float16)a; t.y = (_Float16)b;
    return __builtin_bit_cast(unsigned int, t);
}
__device__ __forceinline__ unsigned short f2hbits(float f) {
    _Float16 h = (_Float16)f;
    return __builtin_bit_cast(unsigned short, h);
}
__device__ __forceinline__ float softplus_f(float x) {
    return fmaxf(x, 0.f) + log1pf(expf(-fabsf(x)));
}

// packed edge record: bits 0-16 = src, bits 17-30 = quantized d index
__device__ __forceinline__ unsigned int ld_rec_nt(const unsigned int* p) {
    return __builtin_nontemporal_load(p);
}
#define REC_SRC(u) ((u) & 0x1FFFFu)
#define REC_T(u)   ((u) >> 17)

// ---------------- table build: tabs[4][TROWS][H] in f16 -------------------
__global__ void build_tables(const float* __restrict__ W_emb1, const float* __restrict__ b_emb1,
                             const float* __restrict__ W_emb2, const float* __restrict__ b_emb2,
                             const float* __restrict__ fW1, const float* __restrict__ fb1,
                             const float* __restrict__ fW2, const float* __restrict__ fb2,
                             unsigned short* __restrict__ tabs)
{
    int which = blockIdx.y;
    const float *W1, *b1, *W2, *b2;
    if (which == 0) { W1 = W_emb1; b1 = b_emb1; W2 = W_emb2; b2 = b_emb2; }
    else {
        int l = which - 1;
        W1 = fW1 + l * H * H; b1 = fb1 + l * H;
        W2 = fW2 + l * H * H; b2 = fb2 + l * H;
    }

    __shared__ float sW1[H * H], sW2[H * H];
    __shared__ float sb1[H], sb2[H];
    __shared__ float sha[4][H], shb[4][H];

    int tid = threadIdx.x;
    for (int i = tid; i < H * H; i += 256) { sW1[i] = W1[i]; sW2[i] = W2[i]; }
    if (tid < H) sb1[tid] = b1[tid];
    else if (tid < 2 * H) sb2[tid - H] = b2[tid - H];
    __syncthreads();

    int wave = tid >> 6, lane = tid & 63;
    int base = blockIdx.x * 64;
    int lim  = min(base + 64, TROWS);

    for (int r = base + wave; r < lim; r += 4) {
        float dv   = (float)r / (float)TBL;
        float mu   = (float)lane / (float)(H - 1);
        float diff = dv - mu;
        float cut  = 0.5f * (cosf(3.14159265358979323846f * dv) + 1.0f);
        float bfj  = expf(-(float)H * diff * diff) * cut;

        sha[wave][lane] = bfj;
        float a = sb1[lane];
        #pragma unroll
        for (int i = 0; i < H; ++i) a = fmaf(sha[wave][i], sW1[i * H + lane], a);
        shb[wave][lane] = softplus_f(a);
        float a2 = sb2[lane];
        #pragma unroll
        for (int i = 0; i < H; ++i) a2 = fmaf(shb[wave][i], sW2[i * H + lane], a2);

        tabs[((size_t)which * TROWS + r) * H + lane] = f2hbits(a2);
    }
}

// ---------------- CSR build: two-level LDS counting sort -------------------
__global__ void coarse_part(const int* __restrict__ src, const int* __restrict__ dst,
                            const float* __restrict__ d, int* __restrict__ ccur,
                            unsigned long long* __restrict__ cbuf, int E, int ncb)
{
    __shared__ int lcnt[256];
    __shared__ int lbase[256];
    int tid = threadIdx.x;
    int e0  = blockIdx.x * (256 * EPT);

    lcnt[tid] = 0;
    __syncthreads();

    int mybin[EPT], myrank[EPT];
    unsigned long long myrec[EPT];
    #pragma unroll
    for (int k = 0; k < EPT; ++k) {
        int e = e0 + k * 256 + tid;
        mybin[k] = -1;
        if (e < E) {
            int v = dst[e];
            int bin = v >> 8;
            float dv = fminf(fmaxf(d[e], 0.f), 1.f);
            int t = (int)(dv * (float)TBL + 0.5f);
            t = min(t, TBL);
            unsigned int p31 = (unsigned int)src[e] | ((unsigned int)t << 17);
            myrec[k]  = (unsigned long long)p31 | ((unsigned long long)(v & 255) << 32);
            mybin[k]  = bin;
            myrank[k] = atomicAdd(&lcnt[bin], 1);
        }
    }
    __syncthreads();

    {
        int c = (tid < ncb) ? lcnt[tid] : 0;
        lbase[tid] = (c > 0) ? atomicAdd(&ccur[tid], c) : 0;
    }
    __syncthreads();

    #pragma unroll
    for (int k = 0; k < EPT; ++k) {
        if (mybin[k] >= 0) {
            cbuf[(size_t)mybin[k] * CAP + lbase[mybin[k]] + myrank[k]] = myrec[k];
        }
    }
}

__global__ void cscan(const int* __restrict__ ccur, int* __restrict__ cstart,
                      int* __restrict__ off, int E, int N, int ncb)
{
    __shared__ int s[256];
    int t = threadIdx.x;
    int v = (t < ncb) ? ccur[t] : 0;
    s[t] = v;
    __syncthreads();
    for (int o = 1; o < 256; o <<= 1) {
        int u = (t >= o) ? s[t - o] : 0;
        __syncthreads();
        s[t] += u;
        __syncthreads();
    }
    if (t < ncb) cstart[t] = s[t] - v;
    if (t == 0) off[N] = E;
}

__global__ void fine_sort(const unsigned long long* __restrict__ cbuf,
                          const int* __restrict__ ccur, const int* __restrict__ cstart,
                          int* __restrict__ off, unsigned int* __restrict__ recs, int N)
{
    __shared__ int lcnt[256];
    __shared__ int ss[256];
    __shared__ int lcur[256];
    int bin  = blockIdx.x;
    int tid  = threadIdx.x;
    int cnt  = ccur[bin];
    int base = cstart[bin];
    const unsigned long long* buf = cbuf + (size_t)bin * CAP;

    lcnt[tid] = 0;
    __syncthreads();
    for (int i = tid; i < cnt; i += 256) {
        int j = (int)((buf[i] >> 32) & 255);
        atomicAdd(&lcnt[j], 1);
    }
    __syncthreads();
    int v = lcnt[tid];
    ss[tid] = v;
    __syncthreads();
    for (int o = 1; o < 256; o <<= 1) {
        int u = (tid >= o) ? ss[tid - o] : 0;
        __syncthreads();
        ss[tid] += u;
        __syncthreads();
    }
    int excl = ss[tid] - v;
    lcur[tid] = excl;
    int node = bin * 256 + tid;
    if (node < N) off[node] = base + excl;
    __syncthreads();
    for (int i = tid; i < cnt; i += 256) {
        unsigned long long r = buf[i];
        int j = (int)((r >> 32) & 255);
        int pos = base + atomicAdd(&lcur[j], 1);
        recs[pos] = (unsigned int)(r & 0x7FFFFFFFu);
    }
}

// ---------------- embedding fused with W_in0 -------------------
// r11 structure: half-wave contiguous split, 8-slot 3-stage pipeline,
// f16 table values converted to f32 accumulators (fma_mix).
__global__ void emb_fused(const int* __restrict__ off, const unsigned int* __restrict__ recs,
                          const unsigned short* __restrict__ tab, const float* __restrict__ W,
                          const float* __restrict__ bvec, unsigned short* __restrict__ yout, int N)
{
    __shared__ unsigned int sWp[H * H / 2];   // packed f16 pairs [i2*64+lane]
    __shared__ float sb[H];
    __shared__ float sx[4][H];
    int tid = threadIdx.x;
    for (int i = tid; i < H * H / 2; i += 256) {
        int i2 = i >> 6, l = i & 63;
        sWp[i] = pack2h(W[(2 * i2) * H + l], W[(2 * i2 + 1) * H + l]);
    }
    if (tid < H) sb[tid] = bvec[tid];
    __syncthreads();

    const unsigned int* tab32 = (const unsigned int*)tab;

    int wave = tid >> 6, lane = tid & 63;
    int half = lane >> 5;
    int li   = lane & 31;

    for (int k = 0; k < 4; ++k) {
        int node = blockIdx.x * 16 + k * 4 + wave;
        if (node >= N) continue;
        int b = off[node], en = off[node + 1];
        int deg = en - b;
        int c0  = (deg + 1) >> 1;
        int p   = b + half * c0;
        int e   = (half == 0) ? (b + c0) : en;

        float a0 = 0.f, a1 = 0.f, a2 = 0.f, a3 = 0.f;

        if (e - p >= 8) {
            unsigned int u0 = ld_rec_nt(recs + p);
            unsigned int u1 = ld_rec_nt(recs + p + 1);
            unsigned int u2 = ld_rec_nt(recs + p + 2);
            unsigned int u3 = ld_rec_nt(recs + p + 3);
            unsigned int tv0 = tab32[(size_t)REC_T(u0) * 32 + li];
            unsigned int tv1 = tab32[(size_t)REC_T(u1) * 32 + li];
            unsigned int tv2 = tab32[(size_t)REC_T(u2) * 32 + li];
            unsigned int tv3 = tab32[(size_t)REC_T(u3) * 32 + li];
            u0 = ld_rec_nt(recs + p + 4);
            u1 = ld_rec_nt(recs + p + 5);
            u2 = ld_rec_nt(recs + p + 6);
            u3 = ld_rec_nt(recs + p + 7);
            while (p + 12 <= e) {
                unsigned int w0 = ld_rec_nt(recs + p + 8);
                unsigned int w1 = ld_rec_nt(recs + p + 9);
                unsigned int w2 = ld_rec_nt(recs + p + 10);
                unsigned int w3 = ld_rec_nt(recs + p + 11);
                unsigned int n0 = tab32[(size_t)REC_T(u0) * 32 + li];
                unsigned int n1 = tab32[(size_t)REC_T(u1) * 32 + li];
                unsigned int n2 = tab32[(size_t)REC_T(u2) * 32 + li];
                unsigned int n3 = tab32[(size_t)REC_T(u3) * 32 + li];
                { h2 t = u2h(tv0); a0 += (float)t.x; a1 += (float)t.y; }
                { h2 t = u2h(tv1); a2 += (float)t.x; a3 += (float)t.y; }
                { h2 t = u2h(tv2); a0 += (float)t.x; a1 += (float)t.y; }
                { h2 t = u2h(tv3); a2 += (float)t.x; a3 += (float)t.y; }
                tv0 = n0; tv1 = n1; tv2 = n2; tv3 = n3;
                u0 = w0; u1 = w1; u2 = w2; u3 = w3;
                p += 4;
            }
            unsigned int n0 = tab32[(size_t)REC_T(u0) * 32 + li];
            unsigned int n1 = tab32[(size_t)REC_T(u1) * 32 + li];
            unsigned int n2 = tab32[(size_t)REC_T(u2) * 32 + li];
            unsigned int n3 = tab32[(size_t)REC_T(u3) * 32 + li];
            { h2 t = u2h(tv0); a0 += (float)t.x; a1 += (float)t.y; }
            { h2 t = u2h(tv1); a2 += (float)t.x; a3 += (float)t.y; }
            { h2 t = u2h(tv2); a0 += (float)t.x; a1 += (float)t.y; }
            { h2 t = u2h(tv3); a2 += (float)t.x; a3 += (float)t.y; }
            { h2 t = u2h(n0);  a0 += (float)t.x; a1 += (float)t.y; }
            { h2 t = u2h(n1);  a2 += (float)t.x; a3 += (float)t.y; }
            { h2 t = u2h(n2);  a0 += (float)t.x; a1 += (float)t.y; }
            { h2 t = u2h(n3);  a2 += (float)t.x; a3 += (float)t.y; }
            p += 8;
        } else if (e - p >= 4) {
            unsigned int u0 = ld_rec_nt(recs + p);
            unsigned int u1 = ld_rec_nt(recs + p + 1);
            unsigned int u2 = ld_rec_nt(recs + p + 2);
            unsigned int u3 = ld_rec_nt(recs + p + 3);
            { h2 t = u2h(tab32[(size_t)REC_T(u0) * 32 + li]); a0 += (float)t.x; a1 += (float)t.y; }
            { h2 t = u2h(tab32[(size_t)REC_T(u1) * 32 + li]); a2 += (float)t.x; a3 += (float)t.y; }
            { h2 t = u2h(tab32[(size_t)REC_T(u2) * 32 + li]); a0 += (float)t.x; a1 += (float)t.y; }
            { h2 t = u2h(tab32[(size_t)REC_T(u3) * 32 + li]); a2 += (float)t.x; a3 += (float)t.y; }
            p += 4;
        }
        for (; p < e; ++p) {
            unsigned int u = ld_rec_nt(recs + p);
            h2 t = u2h(tab32[(size_t)REC_T(u) * 32 + li]);
            a0 += (float)t.x; a1 += (float)t.y;
        }

        float alo = a0 + a2, ahi = a1 + a3;
        alo += __shfl_down(alo, 32);
        ahi += __shfl_down(ahi, 32);
        if (lane < 32) {
            sx[wave][2 * li]     = alo;
            sx[wave][2 * li + 1] = ahi;
        }
        float o = sb[lane];
        #pragma unroll
        for (int i2 = 0; i2 < H / 2; ++i2) {
            h2 w = u2h(sWp[i2 * 64 + lane]);
            o = fmaf(sx[wave][2 * i2],     (float)w.x, o);
            o = fmaf(sx[wave][2 * i2 + 1], (float)w.y, o);
        }
        yout[(size_t)node * H + lane] = f2hbits(o * YSCL);
    }
}

// ---------------- conv layer, fully fused -------------------
// r11 structure + f16 values with f32 accumulation (fma_mix) + y scaling.
template <bool LAST>
__global__ void conv_fused_k(const int* __restrict__ off, const unsigned int* __restrict__ recs,
                             const unsigned short* __restrict__ tab, const unsigned short* __restrict__ y,
                             const float* __restrict__ W_out, const float* __restrict__ b_out,
                             const float* __restrict__ W_in, const float* __restrict__ b_in,
                             unsigned short* __restrict__ yout, float* __restrict__ xout, int N)
{
    __shared__ unsigned int sWo[H * H / 2];
    __shared__ unsigned int sWi[H * H / 2];
    __shared__ float sbo[H], sbi[H];
    __shared__ float sx[4][H];
    int tid = threadIdx.x;
    for (int i = tid; i < H * H / 2; i += 256) {
        int i2 = i >> 6, l = i & 63;
        sWo[i] = pack2h(W_out[(2 * i2) * H + l], W_out[(2 * i2 + 1) * H + l]);
        if (!LAST)
            sWi[i] = pack2h(W_in[(2 * i2) * H + l], W_in[(2 * i2 + 1) * H + l]);
    }
    if (tid < H) sbo[tid] = b_out[tid];
    else if (!LAST && tid < 2 * H) sbi[tid - H] = b_in[tid - H];
    __syncthreads();

    const unsigned int* tab32 = (const unsigned int*)tab;
    const unsigned int* y32   = (const unsigned int*)y;

    int wave = tid >> 6, lane = tid & 63;
    int half = lane >> 5;
    int li   = lane & 31;

    for (int k = 0; k < 4; ++k) {
        int node = blockIdx.x * 16 + k * 4 + wave;
        if (node >= N) continue;
        int b = off[node], en = off[node + 1];
        int deg = en - b;
        int c0  = (deg + 1) >> 1;
        int p   = b + half * c0;
        int e   = (half == 0) ? (b + c0) : en;

        float a0 = 0.f, a1 = 0.f, a2 = 0.f, a3 = 0.f;

        if (e - p >= 8) {
            unsigned int u0 = ld_rec_nt(recs + p);
            unsigned int u1 = ld_rec_nt(recs + p + 1);
            unsigned int u2 = ld_rec_nt(recs + p + 2);
            unsigned int u3 = ld_rec_nt(recs + p + 3);
            unsigned int tv0 = tab32[(size_t)REC_T(u0) * 32 + li];
            unsigned int yv0 = y32[(size_t)REC_SRC(u0) * 32 + li];
            unsigned int tv1 = tab32[(size_t)REC_T(u1) * 32 + li];
            unsigned int yv1 = y32[(size_t)REC_SRC(u1) * 32 + li];
            unsigned int tv2 = tab32[(size_t)REC_T(u2) * 32 + li];
            unsigned int yv2 = y32[(size_t)REC_SRC(u2) * 32 + li];
            unsigned int tv3 = tab32[(size_t)REC_T(u3) * 32 + li];
            unsigned int yv3 = y32[(size_t)REC_SRC(u3) * 32 + li];
            u0 = ld_rec_nt(recs + p + 4);
            u1 = ld_rec_nt(recs + p + 5);
            u2 = ld_rec_nt(recs + p + 6);
            u3 = ld_rec_nt(recs + p + 7);
            while (p + 12 <= e) {
                unsigned int w0 = ld_rec_nt(recs + p + 8);
                unsigned int w1 = ld_rec_nt(recs + p + 9);
                unsigned int w2 = ld_rec_nt(recs + p + 10);
                unsigned int w3 = ld_rec_nt(recs + p + 11);
                unsigned int nt0 = tab32[(size_t)REC_T(u0) * 32 + li];
                unsigned int ny0 = y32[(size_t)REC_SRC(u0) * 32 + li];
                unsigned int nt1 = tab32[(size_t)REC_T(u1) * 32 + li];
                unsigned int ny1 = y32[(size_t)REC_SRC(u1) * 32 + li];
                unsigned int nt2 = tab32[(size_t)REC_T(u2) * 32 + li];
                unsigned int ny2 = y32[(size_t)REC_SRC(u2) * 32 + li];
                unsigned int nt3 = tab32[(size_t)REC_T(u3) * 32 + li];
                unsigned int ny3 = y32[(size_t)REC_SRC(u3) * 32 + li];
                { h2 t = u2h(tv0), v = u2h(yv0);
                  a0 = fmaf((float)v.x, (float)t.x, a0);
                  a1 = fmaf((float)v.y, (float)t.y, a1); }
                { h2 t = u2h(tv1), v = u2h(yv1);
                  a2 = fmaf((float)v.x, (float)t.x, a2);
                  a3 = fmaf((float)v.y, (float)t.y, a3); }
                { h2 t = u2h(tv2), v = u2h(yv2);
                  a0 = fmaf((float)v.x, (float)t.x, a0);
                  a1 = fmaf((float)v.y, (float)t.y, a1); }
                { h2 t = u2h(tv3), v = u2h(yv3);
                  a2 = fmaf((float)v.x, (float)t.x, a2);
                  a3 = fmaf((float)v.y, (float)t.y, a3); }
                tv0 = nt0; yv0 = ny0; tv1 = nt1; yv1 = ny1;
                tv2 = nt2; yv2 = ny2; tv3 = nt3; yv3 = ny3;
                u0 = w0; u1 = w1; u2 = w2; u3 = w3;
                p += 4;
            }
            unsigned int nt0 = tab32[(size_t)REC_T(u0) * 32 + li];
            unsigned int ny0 = y32[(size_t)REC_SRC(u0) * 32 + li];
            unsigned int nt1 = tab32[(size_t)REC_T(u1) * 32 + li];
            unsigned int ny1 = y32[(size_t)REC_SRC(u1) * 32 + li];
            unsigned int nt2 = tab32[(size_t)REC_T(u2) * 32 + li];
            unsigned int ny2 = y32[(size_t)REC_SRC(u2) * 32 + li];
            unsigned int nt3 = tab32[(size_t)REC_T(u3) * 32 + li];
            unsigned int ny3 = y32[(size_t)REC_SRC(u3) * 32 + li];
            { h2 t = u2h(tv0), v = u2h(yv0);
              a0 = fmaf((float)v.x, (float)t.x, a0);
              a1 = fmaf((float)v.y, (float)t.y, a1); }
            { h2 t = u2h(tv1), v = u2h(yv1);
              a2 = fmaf((float)v.x, (float)t.x, a2);
              a3 = fmaf((float)v.y, (float)t.y, a3); }
            { h2 t = u2h(tv2), v = u2h(yv2);
              a0 = fmaf((float)v.x, (float)t.x, a0);
              a1 = fmaf((float)v.y, (float)t.y, a1); }
            { h2 t = u2h(tv3), v = u2h(yv3);
              a2 = fmaf((float)v.x, (float)t.x, a2);
              a3 = fmaf((float)v.y, (float)t.y, a3); }
            { h2 t = u2h(nt0), v = u2h(ny0);
              a0 = fmaf((float)v.x, (float)t.x, a0);
              a1 = fmaf((float)v.y, (float)t.y, a1); }
            { h2 t = u2h(nt1), v = u2h(ny1);
              a2 = fmaf((float)v.x, (float)t.x, a2);
              a3 = fmaf((float)v.y, (float)t.y, a3); }
            { h2 t = u2h(nt2), v = u2h(ny2);
              a0 = fmaf((float)v.x, (float)t.x, a0);
              a1 = fmaf((float)v.y, (float)t.y, a1); }
            { h2 t = u2h(nt3), v = u2h(ny3);
              a2 = fmaf((float)v.x, (float)t.x, a2);
              a3 = fmaf((float)v.y, (float)t.y, a3); }
            p += 8;
        } else if (e - p >= 4) {
            unsigned int u0 = ld_rec_nt(recs + p);
            unsigned int u1 = ld_rec_nt(recs + p + 1);
            unsigned int u2 = ld_rec_nt(recs + p + 2);
            unsigned int u3 = ld_rec_nt(recs + p + 3);
            { h2 t = u2h(tab32[(size_t)REC_T(u0) * 32 + li]), v = u2h(y32[(size_t)REC_SRC(u0) * 32 + li]);
              a0 = fmaf((float)v.x, (float)t.x, a0);
              a1 = fmaf((float)v.y, (float)t.y, a1); }
            { h2 t = u2h(tab32[(size_t)REC_T(u1) * 32 + li]), v = u2h(y32[(size_t)REC_SRC(u1) * 32 + li]);
              a2 = fmaf((float)v.x, (float)t.x, a2);
              a3 = fmaf((float)v.y, (float)t.y, a3); }
            { h2 t = u2h(tab32[(size_t)REC_T(u2) * 32 + li]), v = u2h(y32[(size_t)REC_SRC(u2) * 32 + li]);
              a0 = fmaf((float)v.x, (float)t.x, a0);
              a1 = fmaf((float)v.y, (float)t.y, a1); }
            { h2 t = u2h(tab32[(size_t)REC_T(u3) * 32 + li]), v = u2h(y32[(size_t)REC_SRC(u3) * 32 + li]);
              a2 = fmaf((float)v.x, (float)t.x, a2);
              a3 = fmaf((float)v.y, (float)t.y, a3); }
            p += 4;
        }
        for (; p < e; ++p) {
            unsigned int u = ld_rec_nt(recs + p);
            h2 t = u2h(tab32[(size_t)REC_T(u) * 32 + li]);
            h2 v = u2h(y32[(size_t)REC_SRC(u) * 32 + li]);
            a0 = fmaf((float)v.x, (float)t.x, a0);
            a1 = fmaf((float)v.y, (float)t.y, a1);
        }

        float alo = a0 + a2, ahi = a1 + a3;
        alo += __shfl_down(alo, 32);
        ahi += __shfl_down(ahi, 32);
        if (lane < 32) {
            sx[wave][2 * li]     = alo * YISCL;   // undo y scaling
            sx[wave][2 * li + 1] = ahi * YISCL;
        }
        float o = sbo[lane];
        #pragma unroll
        for (int i2 = 0; i2 < H / 2; ++i2) {
            h2 w = u2h(sWo[i2 * 64 + lane]);
            o = fmaf(sx[wave][2 * i2],     (float)w.x, o);
            o = fmaf(sx[wave][2 * i2 + 1], (float)w.y, o);
        }
        o = fmaxf(o, 0.f);
        if (LAST) {
            xout[(size_t)node * H + lane] = o;
        } else {
            sx[wave][lane] = o;   // same-wave reuse: prior reads are complete
            float o2 = sbi[lane];
            #pragma unroll
            for (int i2 = 0; i2 < H / 2; ++i2) {
                h2 w = u2h(sWi[i2 * 64 + lane]);
                o2 = fmaf(sx[wave][2 * i2],     (float)w.x, o2);
                o2 = fmaf(sx[wave][2 * i2 + 1], (float)w.y, o2);
            }
            yout[(size_t)node * H + lane] = f2hbits(o2 * YSCL);
        }
    }
}

// ---------------- pooling (sorted gid, run-length flush) -------------------
__global__ void pool_kernel(const float* __restrict__ x, const int* __restrict__ gid,
                            float* __restrict__ pooled, float* __restrict__ counts, int N)
{
    int wavesPerBlock = blockDim.x >> 6;
    int wid  = blockIdx.x * wavesPerBlock + (threadIdx.x >> 6);
    int lane = threadIdx.x & 63;
    int totalWaves = gridDim.x * wavesPerBlock;
    int chunk = (N + totalWaves - 1) / totalWaves;
    int beg = wid * chunk, end = min(beg + chunk, N);
    if (beg >= end) return;

    float acc = 0.f;
    int cur = -1, cnt = 0;
    for (int n = beg; n < end; ++n) {
        int g = gid[n];
        if (g != cur) {
            if (cur >= 0) {
                atomicAdd(&pooled[(size_t)cur * H + lane], acc);
                if (lane == 0) atomicAdd(&counts[cur], (float)cnt);
            }
            cur = g; acc = 0.f; cnt = 0;
        }
        acc += x[(size_t)n * H + lane];
        cnt++;
    }
    atomicAdd(&pooled[(size_t)cur * H + lane], acc);
    if (lane == 0) atomicAdd(&counts[cur], (float)cnt);
}

// ---------------- head -------------------
__global__ void head_kernel(const float* __restrict__ pooled, const float* __restrict__ counts,
                            const float* __restrict__ Wfc, const float* __restrict__ bfc,
                            float* __restrict__ out)
{
    int g = blockIdx.x;
    int c = threadIdx.x;
    __shared__ float logits[NCLASSES];
    float cnt = fmaxf(counts[g], 1.0f);
    if (c < NCLASSES) {
        float acc = bfc[c];
        #pragma unroll
        for (int i = 0; i < H; ++i)
            acc = fmaf(pooled[(size_t)g * H + i] / cnt, Wfc[i * NCLASSES + c], acc);
        logits[c] = acc;
    }
    __syncthreads();
    if (c < NCLASSES) {
        float m = -INFINITY;
        #pragma unroll
        for (int k = 0; k < NCLASSES; ++k) m = fmaxf(m, logits[k]);
        float s = 0.f;
        #pragma unroll
        for (int k = 0; k < NCLASSES; ++k) s += expf(logits[k] - m);
        out[g * NCLASSES + c] = logits[c] - m - logf(s);
    }
}

extern "C" void kernel_launch(void* const* d_in, const int* in_sizes, int n_in,
                              void* d_out, int out_size, void* d_ws, size_t ws_size,
                              hipStream_t stream)
{
    const float* d_d    = (const float*)d_in[0];
    const float* W_emb1 = (const float*)d_in[1];
    const float* b_emb1 = (const float*)d_in[2];
    const float* W_emb2 = (const float*)d_in[3];
    const float* b_emb2 = (const float*)d_in[4];
    const float* fW1    = (const float*)d_in[5];
    const float* fb1    = (const float*)d_in[6];
    const float* fW2    = (const float*)d_in[7];
    const float* fb2    = (const float*)d_in[8];
    const float* W_in   = (const float*)d_in[9];
    const float* b_in   = (const float*)d_in[10];
    const float* W_out  = (const float*)d_in[11];
    const float* b_out  = (const float*)d_in[12];
    const float* W_fc   = (const float*)d_in[13];
    const float* b_fc   = (const float*)d_in[14];
    const int*   src    = (const int*)d_in[15];
    const int*   dst    = (const int*)d_in[16];
    const int*   gid    = (const int*)d_in[17];

    const int E = in_sizes[0];
    const int N = in_sizes[17];
    const int ncb = (N + 255) >> 8;   // coarse buckets (<= 256)

    float* out = (float*)d_out;

    // workspace layout (x3 and cbuf share a union region — disjoint lifetimes)
    char* base = (char*)d_ws;
    unsigned int* recs = (unsigned int*)base;          base += (size_t)E * 4;
    unsigned short* tabs = (unsigned short*)base;      base += (size_t)4 * TROWS * H * 2;
    unsigned short* yA   = (unsigned short*)base;      base += (size_t)N * H * 2;
    unsigned short* yB   = (unsigned short*)base;      base += (size_t)N * H * 2;
    size_t usz   = (size_t)N * H * 4;
    size_t csz   = (size_t)ncb * CAP * 8;
    char* uni    = base;                               base += (usz > csz ? usz : csz);
    float* x3    = (float*)uni;
    unsigned long long* cbuf = (unsigned long long*)uni;
    float* pooled= (float*)base;                       base += (size_t)NGRAPHS * H * 4;
    float* counts= (float*)base;                       base += (size_t)NGRAPHS * 4;
    int*  off    = (int*)base;                         base += (size_t)(N + 1) * 4;
    int*  ccur   = (int*)base;                         base += 256 * 4;
    int*  cstart = (int*)base;                         base += 256 * 4;

    const int node_blocks16 = (N + 15) / 16;
    const int part_blocks   = (E + 256 * EPT - 1) / (256 * EPT);

    // 1. f16 MLP lookup tables
    dim3 tg((TROWS + 63) / 64, 4);
    build_tables<<<tg, 256, 0, stream>>>(W_emb1, b_emb1, W_emb2, b_emb2,
                                         fW1, fb1, fW2, fb2, tabs);

    // 2. CSR build: two-level LDS counting sort (no mass device atomics)
    hipMemsetAsync(ccur, 0, 256 * 4, stream);
    coarse_part<<<part_blocks, 256, 0, stream>>>(src, dst, d_d, ccur, cbuf, E, ncb);
    cscan<<<1, 256, 0, stream>>>(ccur, cstart, off, E, N, ncb);
    fine_sort<<<ncb, 256, 0, stream>>>(cbuf, ccur, cstart, off, recs, N);

    // 3. embedding + W_in0 -> yA (scaled f16)
    emb_fused<<<node_blocks16, 256, 0, stream>>>(off, recs, tabs, W_in, b_in, yA, N);

    // 4. conv layers, fully fused (out-proj + next in-proj in epilogue)
    conv_fused_k<false><<<node_blocks16, 256, 0, stream>>>(
        off, recs, tabs + (size_t)1 * TROWS * H, yA,
        W_out, b_out, W_in + (size_t)1 * H * H, b_in + (size_t)1 * H, yB, nullptr, N);
    conv_fused_k<false><<<node_blocks16, 256, 0, stream>>>(
        off, recs, tabs + (size_t)2 * TROWS * H, yB,
        W_out + (size_t)1 * H * H, b_out + (size_t)1 * H,
        W_in + (size_t)2 * H * H, b_in + (size_t)2 * H, yA, nullptr, N);
    conv_fused_k<true><<<node_blocks16, 256, 0, stream>>>(
        off, recs, tabs + (size_t)3 * TROWS * H, yA,
        W_out + (size_t)2 * H * H, b_out + (size_t)2 * H,
        nullptr, nullptr, nullptr, x3, N);

    // 5. pooling
    hipMemsetAsync(pooled, 0, ((size_t)NGRAPHS * H + NGRAPHS) * 4, stream);
    pool_kernel<<<128, 256, 0, stream>>>(x3, gid, pooled, counts, N);

    // 6. head
    head_kernel<<<NGRAPHS, 64, 0, stream>>>(pooled, counts, W_fc, b_fc, out);
}